// Round 4
// baseline (328.197 us; speedup 1.0000x reference)
//
#include <hip/hip_runtime.h>

#define P 256
#define C 28
#define NPIX (P * P)            // 65536
#define NIMG 32
#define Q 7                     // float4s per pixel
#define MASK_ELEMS (NPIX * C)   // 1,835,008

// ---------- prep: bks[i][j][ch] = bk[(i-ch)&255][j][ch] ----------
// Verified in round 0. Writes coalesced; reads scattered but bk (7 MB) is
// L2/L3 resident; measured-calibrated cost ~10 us.
__global__ __launch_bounds__(256) void prep_mask_kernel(
    const float* __restrict__ bk, float* __restrict__ bks) {
    int idx = blockIdx.x * 256 + threadIdx.x;
    if (idx >= MASK_ELEMS) return;
    int ch = idx % C;
    int ij = idx / C;          // i*P + j
    int j = ij & (P - 1);
    int i = ij >> 8;
    int src_row = (i - ch) & (P - 1);
    bks[idx] = bk[(src_row * P + j) * C + ch];
}

// ---------- main ----------
// Round-3 post-mortem: 1024 blocks = exactly one residency set (no block
// replacement); long 32-image per-thread loops ran the x stream at only
// ~2.5 TB/s, while round-0's 32768-short-block kernel hit ~5.2 TB/s
// effective. This version restores block churn:
//   grid = 1024 tiles x 8 image-groups (4 images each) = 8192 blocks,
//   8 waves each -> 4 resident/CU + deep replacement queue.
// Per block: zero LDS, zero barriers.
//   - mask hoist: one coalesced float4 load per thread from prep'd bks
//     (7 KB/block, L2/L3-hot) -- scattered gathers eliminated entirely.
//   - 4 fully-unrolled images: coalesced f4 x-load, dot4, 3-step
//     8-lane shfl_xor reduce, 1 store. Reduction tree identical to the
//     verified round-0 tree (lane q=7 contributes exactly 0).
#define BLK 512                 // 64 pixels * 8 lanes; 8 waves
#define PIX 64
#define IMG_PER_BLK 4
#define TILES (P * (P / PIX))   // 1024
#define NBLOCKS (TILES * (NIMG / IMG_PER_BLK))   // 8192

__global__ __launch_bounds__(BLK) void codednet_main_kernel(
    const float4* __restrict__ x4, const float4* __restrict__ m4,
    float* __restrict__ out) {
    int t = threadIdx.x;
    int n = blockIdx.x;

    int g   = n >> 10;           // image group [0,8)
    int mm  = n & 1023;          // tile index
    // XCD-banded swizzle (same as round 3): xcd residue owns a 32-row band
    // so each XCD's bks slice stays L2-resident.
    int xcd   = mm & 7;
    int loc   = mm >> 3;         // [0,128)
    int i_loc = loc >> 2;        // [0,32)
    int j0b   = loc & 3;         // [0,4)
    int i     = (xcd << 5) + i_loc;
    int pix0  = (i << 8) + (j0b << 6);

    int q  = t & 7;              // lane role in 8-lane pixel group
    int pl = t >> 3;             // 0..63 pixel within tile
    int f  = (pix0 + pl) * Q + q;    // f4 index within an image (q<7)

    // image-invariant mask, hoisted to registers (coalesced load)
    float4 mk = make_float4(0.f, 0.f, 0.f, 0.f);
    if (q < 7) mk = m4[f];

    const size_t istr = (size_t)NPIX * Q;
    int img0 = g * IMG_PER_BLK;

    // batch all 4 loads up front (no barriers -> they stay in flight)
    float4 a0 = make_float4(0.f,0.f,0.f,0.f), a1 = a0, a2 = a0, a3 = a0;
    if (q < 7) {
        const float4* xb = x4 + f;
        a0 = xb[(size_t)(img0 + 0) * istr];
        a1 = xb[(size_t)(img0 + 1) * istr];
        a2 = xb[(size_t)(img0 + 2) * istr];
        a3 = xb[(size_t)(img0 + 3) * istr];
    }

    float r0 = a0.x * mk.x + a0.y * mk.y + a0.z * mk.z + a0.w * mk.w;
    float r1 = a1.x * mk.x + a1.y * mk.y + a1.z * mk.z + a1.w * mk.w;
    float r2 = a2.x * mk.x + a2.y * mk.y + a2.z * mk.z + a2.w * mk.w;
    float r3 = a3.x * mk.x + a3.y * mk.y + a3.z * mk.z + a3.w * mk.w;

    // 8-lane butterflies (masks 1,2,4 stay within the 8-lane group)
    r0 += __shfl_xor(r0, 1); r0 += __shfl_xor(r0, 2); r0 += __shfl_xor(r0, 4);
    r1 += __shfl_xor(r1, 1); r1 += __shfl_xor(r1, 2); r1 += __shfl_xor(r1, 4);
    r2 += __shfl_xor(r2, 1); r2 += __shfl_xor(r2, 2); r2 += __shfl_xor(r2, 4);
    r3 += __shfl_xor(r3, 1); r3 += __shfl_xor(r3, 2); r3 += __shfl_xor(r3, 4);

    if (q == 0) {
        int ob = pix0 + pl;
        out[(img0 + 0) * NPIX + ob] = r0;
        out[(img0 + 1) * NPIX + ob] = r1;
        out[(img0 + 2) * NPIX + ob] = r2;
        out[(img0 + 3) * NPIX + ob] = r3;
    }
}

// Fallback if ws too small (shouldn't trigger; round 0 confirmed ws is large)
__global__ __launch_bounds__(256) void codednet_inline_kernel(
    const float* __restrict__ x, const float* __restrict__ bk,
    float* __restrict__ out) {
    int pid = blockIdx.x * 256 + threadIdx.x;
    int pix = pid & (NPIX - 1);
    int j = pix & (P - 1);
    int i = pix >> 8;
    const float* xp = x + (size_t)pid * C;
    float acc = 0.f;
#pragma unroll
    for (int ch = 0; ch < C; ++ch) {
        int src_row = (i - ch) & (P - 1);
        acc += xp[ch] * bk[(src_row * P + j) * C + ch];
    }
    out[pid] = acc;
}

extern "C" void kernel_launch(void* const* d_in, const int* in_sizes, int n_in,
                              void* d_out, int out_size, void* d_ws, size_t ws_size,
                              hipStream_t stream) {
    const float* x  = (const float*)d_in[0];
    const float* bk = (const float*)d_in[1];
    float* out = (float*)d_out;
    const int total = out_size;                  // 32*256*256

    if (ws_size >= (size_t)MASK_ELEMS * sizeof(float)) {
        float* bks = (float*)d_ws;
        prep_mask_kernel<<<(MASK_ELEMS + 255) / 256, 256, 0, stream>>>(bk, bks);
        codednet_main_kernel<<<NBLOCKS, BLK, 0, stream>>>(
            (const float4*)x, (const float4*)bks, out);
    } else {
        codednet_inline_kernel<<<(total + 255) / 256, 256, 0, stream>>>(x, bk, out);
    }
}